// Round 1
// baseline (952.779 us; speedup 1.0000x reference)
//
#include <hip/hip_runtime.h>

// Problem constants (from reference)
#define Hh 256
#define Ww 256
#define Cc 32
#define NV 16
#define NN 4
#define NL 4

// One block = one (n, v, y) row; threadIdx.x = x.
// Each thread: determine winning layer for its pixel (highest l whose shifted
// source is in-bounds and depth[src]==l), then copy all 32 channels (or zeros).
__global__ __launch_bounds__(256) void warp_kernel(
    const float* __restrict__ feats,      // [NV, C, H, W]
    const int*   __restrict__ depth,      // [NV, 1, H, W]
    const float* __restrict__ novel,      // [NN, 2]
    const float* __restrict__ vpos,       // [NV, 2]
    float*       __restrict__ out)        // [NN, NV, C, H, W]
{
    const int x = threadIdx.x;
    const int y = blockIdx.x & (Hh - 1);
    const int v = (blockIdx.x >> 8) & (NV - 1);
    const int n = blockIdx.x >> 12;

    const float dvx = vpos[2 * v]     - novel[2 * n];
    const float dvy = vpos[2 * v + 1] - novel[2 * n + 1];
    const float diop[NL] = {0.5f, 1.0f, 2.0f, 3.0f};

    const int* dv = depth + v * (Hh * Ww);

    int winner = -1;  // source offset sy*W+sx, or -1
    #pragma unroll
    for (int l = NL - 1; l >= 0; --l) {
        // match reference: round(((vpos - novel) * diop) * (F_CAM*FEAT_DIM)), RNE
        const int dx = (int)rintf((dvx * diop[l]) * 128.0f);
        const int dy = (int)rintf((dvy * diop[l]) * 128.0f);
        const int sy = y - dy;
        const int sx = x - dx;
        if (winner < 0 && sy >= 0 && sy < Hh && sx >= 0 && sx < Ww) {
            if (dv[sy * Ww + sx] == l) winner = sy * Ww + sx;
        }
    }

    const size_t plane = (size_t)Hh * Ww;
    float* ob = out + ((size_t)(n * NV + v) * Cc) * plane + (size_t)y * Ww + x;
    const float* fv = feats + (size_t)v * Cc * plane;

    if (winner >= 0) {
        #pragma unroll 8
        for (int c = 0; c < Cc; ++c)
            ob[(size_t)c * plane] = fv[(size_t)c * plane + winner];
    } else {
        #pragma unroll 8
        for (int c = 0; c < Cc; ++c)
            ob[(size_t)c * plane] = 0.0f;
    }
}

extern "C" void kernel_launch(void* const* d_in, const int* in_sizes, int n_in,
                              void* d_out, int out_size, void* d_ws, size_t ws_size,
                              hipStream_t stream) {
    const float* feats = (const float*)d_in[0];
    const int*   depth = (const int*)d_in[1];
    const float* novel = (const float*)d_in[2];
    const float* vpos  = (const float*)d_in[3];
    float* out = (float*)d_out;

    dim3 grid(NN * NV * Hh);  // 16384 blocks: (n, v, y)
    dim3 block(Ww);           // 256 threads: x
    warp_kernel<<<grid, block, 0, stream>>>(feats, depth, novel, vpos, out);
}